// Round 2
// baseline (256.113 us; speedup 1.0000x reference)
//
#include <hip/hip_runtime.h>
#include <hip/hip_bf16.h>

// CSM_62216896250023: emb gather (16384,7,1024) -> 4 stacked depthwise seq-convs
// with sigmoid, seq 7->6->5->3->1, out (16384,1024) f32.
//
// R2 changes vs R1 (100us/dispatch, VALUBusy 57%, HBM 37%):
//  - sigmoid(x) = rcp(1 + exp2(y)) with conv weights prescaled by -log2(e):
//    kills the per-sigmoid v_mul (60/thread -> 10 one-time pk_muls).
//  - float2 ext-vector arithmetic -> v_pk_fma_f32 / v_pk_add_f32 (halves
//    full-rate VALU issue count).
//  - indices loaded via uniform (blockIdx-only) addresses -> s_load; no LDS,
//    no __syncthreads.

constexpr int EMBED = 1024;
constexpr int SEQ   = 7;

typedef float f2 __attribute__((ext_vector_type(2)));

__device__ __forceinline__ f2 sig2(f2 y) {
    // y is already  -log2(e) * (pre-activation);  sigmoid = 1/(1 + 2^y)
    f2 u;
    u.x = __builtin_amdgcn_exp2f(y.x);
    u.y = __builtin_amdgcn_exp2f(y.y);
    f2 d = u + (f2){1.0f, 1.0f};          // v_pk_add_f32
    f2 r;
    r.x = __builtin_amdgcn_rcpf(d.x);
    r.y = __builtin_amdgcn_rcpf(d.y);
    return r;
}

__global__ __launch_bounds__(256) void CSM_62216896250023_kernel(
    const int*   __restrict__ X,
    const float* __restrict__ emb,
    const float* __restrict__ c1,
    const float* __restrict__ c2,
    const float* __restrict__ c3,
    const float* __restrict__ c4,
    float*       __restrict__ out)
{
    const int b = blockIdx.x;
    const int e = threadIdx.x << 2;       // float4 offset in embed dim

    // Uniform addresses -> scalar loads, no barrier needed.
    int idx[SEQ];
#pragma unroll
    for (int t = 0; t < SEQ; ++t) idx[t] = X[b * SEQ + t];

    // Issue all 7 gathers up front (stay in flight under vmcnt).
    f2 v[SEQ][2];
#pragma unroll
    for (int t = 0; t < SEQ; ++t) {
        const float4 f = *(const float4*)(emb + (size_t)idx[t] * EMBED + e);
        v[t][0] = (f2){f.x, f.y};
        v[t][1] = (f2){f.z, f.w};
    }

    // Conv weights, prescaled by -log2(e) so sigmoid needs no multiply.
    const float NL2E = -1.44269504088896f;
    f2 k1[2][2], k2[2][2], k3[3][2], k4[3][2];
#pragma unroll
    for (int t = 0; t < 2; ++t) {
        float4 f = *(const float4*)(c1 + t * EMBED + e);
        k1[t][0] = (f2){f.x * NL2E, f.y * NL2E};
        k1[t][1] = (f2){f.z * NL2E, f.w * NL2E};
        f = *(const float4*)(c2 + t * EMBED + e);
        k2[t][0] = (f2){f.x * NL2E, f.y * NL2E};
        k2[t][1] = (f2){f.z * NL2E, f.w * NL2E};
    }
#pragma unroll
    for (int t = 0; t < 3; ++t) {
        float4 f = *(const float4*)(c3 + t * EMBED + e);
        k3[t][0] = (f2){f.x * NL2E, f.y * NL2E};
        k3[t][1] = (f2){f.z * NL2E, f.w * NL2E};
        f = *(const float4*)(c4 + t * EMBED + e);
        k4[t][0] = (f2){f.x * NL2E, f.y * NL2E};
        k4[t][1] = (f2){f.z * NL2E, f.w * NL2E};
    }

    f2 o[2];
#pragma unroll
    for (int p = 0; p < 2; ++p) {         // two float2 channel pairs
        f2 h1[6];
#pragma unroll
        for (int l = 0; l < 6; ++l)
            h1[l] = sig2(v[l][p] * k1[0][p] + v[l + 1][p] * k1[1][p]);

        f2 h2[5];
#pragma unroll
        for (int l = 0; l < 5; ++l)
            h2[l] = sig2(h1[l] * k2[0][p] + h1[l + 1] * k2[1][p]);

        f2 h3[3];
#pragma unroll
        for (int l = 0; l < 3; ++l)
            h3[l] = sig2(h2[l] * k3[0][p] + h2[l + 1] * k3[1][p] + h2[l + 2] * k3[2][p]);

        o[p] = sig2(h3[0] * k4[0][p] + h3[1] * k4[1][p] + h3[2] * k4[2][p]);
    }

    float4 of;
    of.x = o[0].x; of.y = o[0].y; of.z = o[1].x; of.w = o[1].y;
    *(float4*)(out + (size_t)b * EMBED + e) = of;
}

extern "C" void kernel_launch(void* const* d_in, const int* in_sizes, int n_in,
                              void* d_out, int out_size, void* d_ws, size_t ws_size,
                              hipStream_t stream) {
    const int*   X   = (const int*)d_in[0];
    const float* emb = (const float*)d_in[1];
    const float* c1  = (const float*)d_in[2];
    const float* c2  = (const float*)d_in[3];
    const float* c3  = (const float*)d_in[4];
    const float* c4  = (const float*)d_in[5];
    float* out = (float*)d_out;

    const int batch = in_sizes[0] / SEQ;   // 16384
    CSM_62216896250023_kernel<<<batch, 256, 0, stream>>>(X, emb, c1, c2, c3, c4, out);
}

// Round 3
// 246.905 us; speedup vs baseline: 1.0373x; 1.0373x over previous
//
#include <hip/hip_runtime.h>

// CSM_62216896250023: emb gather (16384,7,1024) -> 4 stacked depthwise seq-convs
// with sigmoid, seq 7->6->5->3->1, out (16384,1024) f32.
//
// R3: latency-bound fix (R1/R2 both pinned at ~101us with identical FETCH but
// very different VALUBusy -> memory latency, not BW or VALU, is the limiter;
// VGPR_Count=32 forced serialized gathers).
//  - 8 rows per block (grid 2048): weights loaded + prescaled ONCE per block.
//  - double-buffered row pipeline: gathers for row r+1 in flight while
//    computing row r (per-wave MLP instead of relying on TLP).
//  - __launch_bounds__(256,4): 128-VGPR budget so both 28-VGPR row buffers +
//    40 VGPRs of weights stay live without spills.

constexpr int EMBED = 1024;
constexpr int SEQ   = 7;
constexpr int ROWS  = 8;    // batch rows per block

typedef float f2 __attribute__((ext_vector_type(2)));

__device__ __forceinline__ f2 sig2(f2 y) {
    // y = -log2(e) * preact;  sigmoid = 1/(1 + 2^y)
    f2 u;
    u.x = __builtin_amdgcn_exp2f(y.x);
    u.y = __builtin_amdgcn_exp2f(y.y);
    f2 d = u + (f2){1.0f, 1.0f};
    f2 r;
    r.x = __builtin_amdgcn_rcpf(d.x);
    r.y = __builtin_amdgcn_rcpf(d.y);
    return r;
}

struct Weights {
    f2 k1[2][2], k2[2][2], k3[3][2], k4[3][2];
};

__device__ __forceinline__ void gather_row(const float* __restrict__ emb,
                                           const int* __restrict__ X,
                                           int row, int e, f2 v[SEQ][2]) {
#pragma unroll
    for (int t = 0; t < SEQ; ++t) {
        const int id = X[row * SEQ + t];               // uniform -> s_load
        const float4 f = *(const float4*)(emb + (size_t)id * EMBED + e);
        v[t][0] = (f2){f.x, f.y};
        v[t][1] = (f2){f.z, f.w};
    }
}

__device__ __forceinline__ void compute_row(const f2 v[SEQ][2], const Weights& w,
                                            float* __restrict__ outp) {
    f2 o[2];
#pragma unroll
    for (int p = 0; p < 2; ++p) {
        f2 h1[6];
#pragma unroll
        for (int l = 0; l < 6; ++l)
            h1[l] = sig2(v[l][p] * w.k1[0][p] + v[l + 1][p] * w.k1[1][p]);
        f2 h2[5];
#pragma unroll
        for (int l = 0; l < 5; ++l)
            h2[l] = sig2(h1[l] * w.k2[0][p] + h1[l + 1] * w.k2[1][p]);
        f2 h3[3];
#pragma unroll
        for (int l = 0; l < 3; ++l)
            h3[l] = sig2(h2[l] * w.k3[0][p] + h2[l + 1] * w.k3[1][p] + h2[l + 2] * w.k3[2][p]);
        o[p] = sig2(h3[0] * w.k4[0][p] + h3[1] * w.k4[1][p] + h3[2] * w.k4[2][p]);
    }
    float4 of;
    of.x = o[0].x; of.y = o[0].y; of.z = o[1].x; of.w = o[1].y;
    *(float4*)outp = of;
}

__global__ __launch_bounds__(256, 4) void CSM_62216896250023_kernel(
    const int*   __restrict__ X,
    const float* __restrict__ emb,
    const float* __restrict__ c1,
    const float* __restrict__ c2,
    const float* __restrict__ c3,
    const float* __restrict__ c4,
    float*       __restrict__ out)
{
    const int b0 = blockIdx.x * ROWS;
    const int e  = threadIdx.x << 2;

    // Load + prescale weights once per block.
    const float NL2E = -1.44269504088896f;
    Weights w;
#pragma unroll
    for (int t = 0; t < 2; ++t) {
        float4 f = *(const float4*)(c1 + t * EMBED + e);
        w.k1[t][0] = (f2){f.x * NL2E, f.y * NL2E};
        w.k1[t][1] = (f2){f.z * NL2E, f.w * NL2E};
        f = *(const float4*)(c2 + t * EMBED + e);
        w.k2[t][0] = (f2){f.x * NL2E, f.y * NL2E};
        w.k2[t][1] = (f2){f.z * NL2E, f.w * NL2E};
    }
#pragma unroll
    for (int t = 0; t < 3; ++t) {
        float4 f = *(const float4*)(c3 + t * EMBED + e);
        w.k3[t][0] = (f2){f.x * NL2E, f.y * NL2E};
        w.k3[t][1] = (f2){f.z * NL2E, f.w * NL2E};
        f = *(const float4*)(c4 + t * EMBED + e);
        w.k4[t][0] = (f2){f.x * NL2E, f.y * NL2E};
        w.k4[t][1] = (f2){f.z * NL2E, f.w * NL2E};
    }

    // Double-buffered row pipeline: gathers for r+1 in flight during compute(r).
    f2 va[SEQ][2], vb[SEQ][2];
    gather_row(emb, X, b0, e, va);
#pragma unroll
    for (int r = 0; r < ROWS; ++r) {
        if (r & 1) {
            if (r + 1 < ROWS) gather_row(emb, X, b0 + r + 1, e, va);
            compute_row(vb, w, out + (size_t)(b0 + r) * EMBED + e);
        } else {
            if (r + 1 < ROWS) gather_row(emb, X, b0 + r + 1, e, vb);
            compute_row(va, w, out + (size_t)(b0 + r) * EMBED + e);
        }
    }
}

extern "C" void kernel_launch(void* const* d_in, const int* in_sizes, int n_in,
                              void* d_out, int out_size, void* d_ws, size_t ws_size,
                              hipStream_t stream) {
    const int*   X   = (const int*)d_in[0];
    const float* emb = (const float*)d_in[1];
    const float* c1  = (const float*)d_in[2];
    const float* c2  = (const float*)d_in[3];
    const float* c3  = (const float*)d_in[4];
    const float* c4  = (const float*)d_in[5];
    float* out = (float*)d_out;

    const int batch = in_sizes[0] / SEQ;        // 16384
    CSM_62216896250023_kernel<<<batch / ROWS, 256, 0, stream>>>(X, emb, c1, c2, c3, c4, out);
}